// Round 1
// baseline (1139.976 us; speedup 1.0000x reference)
//
#include <hip/hip_runtime.h>

// BinarizeLayer forward:
//   out[b, 0:16]    = x[b, 0:16]                      (disc passthrough)
//   out[b, 16:272]  = one_hot over K1=16 bins, per feature f (16 features)
//   out[b, 272:400] = one_hot over K2=8  bins, per feature f
//   out[B*400]      = kmeans loss (sum_f mean_b sum_k d*softmax(-d)), both configs
//
// Forward value of `s2 + stop_grad(oh - s2)` is the one-hot of argmax(s2).
// argmax(softmax(-100 d)) with first-occurrence tie-break is replicated
// bit-faithfully: fp32 cumsum centers, d=(c-mu)^2, z=-100*d, max-shift,
// expf, ordered fp32 sum, IEEE division, strict-> scan (keeps first).
// fp contract(off) so hipcc does not fma-contract the tie-sensitive path.

constexpr int kB      = 524288;
constexpr int kF      = 16;
constexpr int kK1     = 16;
constexpr int kK2     = 8;
constexpr int kRowIn  = 32;    // DISC + F
constexpr int kRowOut = 400;   // DISC + F*K1 + F*K2
constexpr float kEps  = 0.001f;

__global__ __launch_bounds__(256) void binlayer_main(
    const float* __restrict__ x,
    const float* __restrict__ interval,
    const float* __restrict__ interval2,
    const float* __restrict__ i_min,
    float* __restrict__ out,
    double* __restrict__ loss_acc)
{
#pragma clang fp contract(off)
    __shared__ float sC1[kF][kK1];
    __shared__ float sC2[kF][kK2];
    __shared__ float sCont[256 * 17];   // +17 stride: 2 lanes/bank (free)

    const int tid = threadIdx.x;

    // centers: i_min + fp32 cumsum of max(interval, eps), in k order
    if (tid < kF) {
        const float base = i_min[tid];
        float run = 0.f;
        for (int k = 0; k < kK1; ++k) {
            run += fmaxf(interval[tid * kK1 + k], kEps);
            sC1[tid][k] = base + run;
        }
        run = 0.f;
        for (int k = 0; k < kK2; ++k) {
            run += fmaxf(interval2[tid * kK2 + k], kEps);
            sC2[tid][k] = base + run;
        }
    }

    const long long row = (long long)blockIdx.x * 256 + tid;
    const float4* __restrict__ xin = (const float4*)(x + row * kRowIn);
    float4* __restrict__ o4 = (float4*)(out + row * kRowOut);

    float4 xd0 = xin[0], xd1 = xin[1], xd2 = xin[2], xd3 = xin[3];
    float4 xc0 = xin[4], xc1 = xin[5], xc2 = xin[6], xc3 = xin[7];

    // disc passthrough
    o4[0] = xd0; o4[1] = xd1; o4[2] = xd2; o4[3] = xd3;

    // stage cont to LDS (scalar writes: base not 16B-aligned by design)
    float* myc = &sCont[tid * 17];
    myc[0]  = xc0.x; myc[1]  = xc0.y; myc[2]  = xc0.z; myc[3]  = xc0.w;
    myc[4]  = xc1.x; myc[5]  = xc1.y; myc[6]  = xc1.z; myc[7]  = xc1.w;
    myc[8]  = xc2.x; myc[9]  = xc2.y; myc[10] = xc2.z; myc[11] = xc2.w;
    myc[12] = xc3.x; myc[13] = xc3.y; myc[14] = xc3.z; myc[15] = xc3.w;

    __syncthreads();

    double lacc = 0.0;

#pragma unroll 1
    for (int f = 0; f < kF; ++f) {
        const float c = myc[f];

        // ================= config 1: K1 = 16 =================
        {
            float dd[kK1];
#pragma unroll
            for (int k = 0; k < kK1; ++k) { float t = c - sC1[f][k]; dd[k] = t * t; }

            // loss: sum_k d*softmax(-d). Smooth path; skip max-shift (no overflow,
            // d in [0, ~4]); rounding delta far under threshold.
            float se = 0.f, sde = 0.f;
#pragma unroll
            for (int k = 0; k < kK1; ++k) {
                float e = expf(-dd[k]);
                se += e; sde += dd[k] * e;
            }
            lacc += (double)(sde / se);

            // argmax(softmax(-100 d)) — bit-faithful replication
            float z[kK1];
#pragma unroll
            for (int k = 0; k < kK1; ++k) z[k] = -100.0f * dd[k];
            float m = z[0];
#pragma unroll
            for (int k = 1; k < kK1; ++k) m = fmaxf(m, z[k]);
            float e2[kK1]; float ss = 0.f;
#pragma unroll
            for (int k = 0; k < kK1; ++k) { e2[k] = expf(z[k] - m); ss += e2[k]; }
            int kmax = 0; float pmax = e2[0] / ss;
#pragma unroll
            for (int k = 1; k < kK1; ++k) {
                float p = e2[k] / ss;               // IEEE div, like numpy
                if (p > pmax) { pmax = p; kmax = k; }  // strict >: first occurrence wins
            }

#pragma unroll
            for (int q = 0; q < kK1 / 4; ++q) {
                float4 o;
                o.x = (kmax == 4 * q + 0) ? 1.f : 0.f;
                o.y = (kmax == 4 * q + 1) ? 1.f : 0.f;
                o.z = (kmax == 4 * q + 2) ? 1.f : 0.f;
                o.w = (kmax == 4 * q + 3) ? 1.f : 0.f;
                o4[4 + f * 4 + q] = o;              // floats [16 + f*16 ...]
            }
        }

        // ================= config 2: K2 = 8 =================
        {
            float dd[kK2];
#pragma unroll
            for (int k = 0; k < kK2; ++k) { float t = c - sC2[f][k]; dd[k] = t * t; }

            float se = 0.f, sde = 0.f;
#pragma unroll
            for (int k = 0; k < kK2; ++k) {
                float e = expf(-dd[k]);
                se += e; sde += dd[k] * e;
            }
            lacc += (double)(sde / se);

            float z[kK2];
#pragma unroll
            for (int k = 0; k < kK2; ++k) z[k] = -100.0f * dd[k];
            float m = z[0];
#pragma unroll
            for (int k = 1; k < kK2; ++k) m = fmaxf(m, z[k]);
            float e2[kK2]; float ss = 0.f;
#pragma unroll
            for (int k = 0; k < kK2; ++k) { e2[k] = expf(z[k] - m); ss += e2[k]; }
            int kmax = 0; float pmax = e2[0] / ss;
#pragma unroll
            for (int k = 1; k < kK2; ++k) {
                float p = e2[k] / ss;
                if (p > pmax) { pmax = p; kmax = k; }
            }

#pragma unroll
            for (int q = 0; q < kK2 / 4; ++q) {
                float4 o;
                o.x = (kmax == 4 * q + 0) ? 1.f : 0.f;
                o.y = (kmax == 4 * q + 1) ? 1.f : 0.f;
                o.z = (kmax == 4 * q + 2) ? 1.f : 0.f;
                o.w = (kmax == 4 * q + 3) ? 1.f : 0.f;
                o4[68 + f * 2 + q] = o;             // floats [272 + f*8 ...]
            }
        }
    }

    // loss reduction: wave shuffle-reduce (64 lanes), one atomic per wave
#pragma unroll
    for (int off = 32; off > 0; off >>= 1) lacc += __shfl_down(lacc, off);
    if ((tid & 63) == 0) atomicAdd(loss_acc, lacc);
}

__global__ void binlayer_finalize(const double* __restrict__ acc,
                                  float* __restrict__ out)
{
    // loss = sum_f mean_b (...) summed over both configs = total / B
    out[(long long)kB * kRowOut] = (float)(*acc * (1.0 / (double)kB));
}

extern "C" void kernel_launch(void* const* d_in, const int* in_sizes, int n_in,
                              void* d_out, int out_size, void* d_ws, size_t ws_size,
                              hipStream_t stream)
{
    const float* x    = (const float*)d_in[0];
    const float* itv1 = (const float*)d_in[1];
    const float* itv2 = (const float*)d_in[2];
    const float* imin = (const float*)d_in[3];
    float* out = (float*)d_out;
    double* acc = (double*)d_ws;

    hipMemsetAsync(acc, 0, sizeof(double), stream);
    binlayer_main<<<kB / 256, 256, 0, stream>>>(x, itv1, itv2, imin, out, acc);
    binlayer_finalize<<<1, 1, 0, stream>>>(acc, out);
}

// Round 2
// 961.253 us; speedup vs baseline: 1.1859x; 1.1859x over previous
//
#include <hip/hip_runtime.h>

// BinarizeLayer forward, restructured for coalescing:
//   phase 1: coalesced float4 tile load (256 rows x 32 f32) -> LDS (stride 33, conflict-free)
//   phase 2: one row per thread -- identical fp32 math to the verified r1 kernel
//            (fp32 cumsum centers, d=(c-mu)^2, z=-100d, max-shift, expf, ordered sum).
//            argmax(softmax) == first-occurrence argmax(e2) UNLESS division by the
//            common ss creates a tie, which requires e2[j] >= emax*(1-2^-23); we
//            detect that conservatively and take the exact IEEE-div path only then.
//            Packed result (kmax1 | kmax2<<4) -> LDS.
//   phase 3: 100 fully-coalesced float4 stores over the block's contiguous
//            400 KB output region, one-hot expanded on the fly.

constexpr int kB      = 524288;
constexpr int kF      = 16;
constexpr int kK1     = 16;
constexpr int kK2     = 8;
constexpr int kRowIn  = 32;    // DISC + F
constexpr int kRowOut = 400;   // DISC + F*K1 + F*K2
constexpr float kEps  = 0.001f;
constexpr int kTPB    = 256;   // threads per block == rows per block
constexpr int kC4     = kRowOut / 4;   // 100 float4 chunks per row
constexpr int kXStride = 33;   // LDS row stride in floats (conflict-free)

template <int K>
__device__ __forceinline__ int soft_argmax_loss(const float* __restrict__ dd,
                                                double& lacc)
{
#pragma clang fp contract(off)
    // ---- loss term: sum_k d * softmax(-d) (smooth, threshold-tolerant) ----
    float se = 0.f, sde = 0.f;
#pragma unroll
    for (int k = 0; k < K; ++k) {
        float e = expf(-dd[k]);
        se += e; sde += dd[k] * e;
    }
    lacc += (double)(sde / se);

    // ---- argmax(softmax(-100*d)) : bit-faithful to fp32 reference ----
    float z[K];
#pragma unroll
    for (int k = 0; k < K; ++k) z[k] = -100.0f * dd[k];
    float m = z[0];
#pragma unroll
    for (int k = 1; k < K; ++k) m = fmaxf(m, z[k]);
    float e2[K]; float ss = 0.f;
#pragma unroll
    for (int k = 0; k < K; ++k) { e2[k] = expf(z[k] - m); ss += e2[k]; }

    // first-occurrence argmax over e2 (strict >)
    int kmax = 0; float emax = e2[0];
#pragma unroll
    for (int k = 1; k < K; ++k) {
        if (e2[k] > emax) { emax = e2[k]; kmax = k; }
    }

    // Division by common positive ss is order-preserving; argmax(p) can only
    // differ if p[j]==p[kmax] for some j<kmax, which needs e2[j] within ~1 ulp
    // relative of emax. Conservative filter (3 ulp margin), exact divide path
    // only when a candidate exists (exec-masked, ~never taken).
    bool cand = false;
#pragma unroll
    for (int k = 0; k < K; ++k)
        cand |= (k < kmax) & (e2[k] >= emax * 0.99999964f);
    if (cand) {
        float pmax = emax / ss;          // IEEE div, like numpy
        for (int j = 0; j < kmax; ++j) {
            if (e2[j] / ss == pmax) { kmax = j; break; }  // first occurrence wins
        }
    }
    return kmax;
}

__global__ __launch_bounds__(kTPB) void binlayer_main(
    const float* __restrict__ x,
    const float* __restrict__ interval,
    const float* __restrict__ interval2,
    const float* __restrict__ i_min,
    float* __restrict__ out,
    double* __restrict__ loss_acc)
{
#pragma clang fp contract(off)
    __shared__ float sC1[kF][kK1];
    __shared__ float sC2[kF][kK2];
    __shared__ float sX[kTPB * kXStride];
    __shared__ unsigned char sIdx[kTPB * kF];

    const int tid = threadIdx.x;

    // centers: i_min + fp32 cumsum of max(interval, eps), in k order
    if (tid < kF) {
        const float base = i_min[tid];
        float run = 0.f;
        for (int k = 0; k < kK1; ++k) {
            run += fmaxf(interval[tid * kK1 + k], kEps);
            sC1[tid][k] = base + run;
        }
        run = 0.f;
        for (int k = 0; k < kK2; ++k) {
            run += fmaxf(interval2[tid * kK2 + k], kEps);
            sC2[tid][k] = base + run;
        }
    }

    const long long rowBase = (long long)blockIdx.x * kTPB;

    // ---------------- phase 1: coalesced tile load -> LDS ----------------
    const float4* __restrict__ xin4 = (const float4*)(x + rowBase * kRowIn);
#pragma unroll
    for (int i = 0; i < (kTPB * kRowIn / 4) / kTPB; ++i) {   // 8 iters
        int flat = i * kTPB + tid;                 // 0..2047 float4s
        float4 v = xin4[flat];
        int r = flat >> 3, c4 = flat & 7;
        float* p = &sX[r * kXStride + c4 * 4];
        p[0] = v.x; p[1] = v.y; p[2] = v.z; p[3] = v.w;
    }
    __syncthreads();

    // ---------------- phase 2: one row per thread ----------------
    double lacc = 0.0;
    const float* __restrict__ myc = &sX[tid * kXStride + 16];

#pragma unroll 1
    for (int f = 0; f < kF; ++f) {
        const float c = myc[f];

        float dd1[kK1];
#pragma unroll
        for (int k = 0; k < kK1; ++k) { float t = c - sC1[f][k]; dd1[k] = t * t; }
        int k1 = soft_argmax_loss<kK1>(dd1, lacc);

        float dd2[kK2];
#pragma unroll
        for (int k = 0; k < kK2; ++k) { float t = c - sC2[f][k]; dd2[k] = t * t; }
        int k2 = soft_argmax_loss<kK2>(dd2, lacc);

        sIdx[tid * kF + f] = (unsigned char)(k1 | (k2 << 4));
    }

    // loss reduction: wave shuffle-reduce, one atomic per wave
#pragma unroll
    for (int off = 32; off > 0; off >>= 1) lacc += __shfl_down(lacc, off);
    if ((tid & 63) == 0) atomicAdd(loss_acc, lacc);

    __syncthreads();

    // ---------------- phase 3: fully coalesced stores ----------------
    float4* __restrict__ o4 = (float4*)(out + rowBase * kRowOut);
#pragma unroll 1
    for (int i = 0; i < kC4; ++i) {                  // 100 iters
        unsigned idx = (unsigned)(i * kTPB + tid);   // 0..25599
        unsigned r = idx / 100u;                     // row in tile
        unsigned c = idx - r * 100u;                 // float4 chunk in row
        float4 o;
        if (c < 4u) {
            const float* p = &sX[r * kXStride + c * 4u];
            o.x = p[0]; o.y = p[1]; o.z = p[2]; o.w = p[3];
        } else if (c < 68u) {
            unsigned u = c - 4u, f = u >> 2, q = (u & 3u) * 4u;
            unsigned k = sIdx[r * kF + f] & 15u;
            o.x = (k == q + 0u) ? 1.f : 0.f;
            o.y = (k == q + 1u) ? 1.f : 0.f;
            o.z = (k == q + 2u) ? 1.f : 0.f;
            o.w = (k == q + 3u) ? 1.f : 0.f;
        } else {
            unsigned u = c - 68u, f = u >> 1, q = (u & 1u) * 4u;
            unsigned k = (unsigned)(sIdx[r * kF + f]) >> 4;
            o.x = (k == q + 0u) ? 1.f : 0.f;
            o.y = (k == q + 1u) ? 1.f : 0.f;
            o.z = (k == q + 2u) ? 1.f : 0.f;
            o.w = (k == q + 3u) ? 1.f : 0.f;
        }
        o4[idx] = o;
    }
}

__global__ void binlayer_finalize(const double* __restrict__ acc,
                                  float* __restrict__ out)
{
    out[(long long)kB * kRowOut] = (float)(*acc * (1.0 / (double)kB));
}

extern "C" void kernel_launch(void* const* d_in, const int* in_sizes, int n_in,
                              void* d_out, int out_size, void* d_ws, size_t ws_size,
                              hipStream_t stream)
{
    const float* x    = (const float*)d_in[0];
    const float* itv1 = (const float*)d_in[1];
    const float* itv2 = (const float*)d_in[2];
    const float* imin = (const float*)d_in[3];
    float* out = (float*)d_out;
    double* acc = (double*)d_ws;

    hipMemsetAsync(acc, 0, sizeof(double), stream);
    binlayer_main<<<kB / kTPB, kTPB, 0, stream>>>(x, itv1, itv2, imin, out, acc);
    binlayer_finalize<<<1, 1, 0, stream>>>(acc, out);
}

// Round 3
// 891.452 us; speedup vs baseline: 1.2788x; 1.0783x over previous
//
#include <hip/hip_runtime.h>

// BinarizeLayer forward:
//   phase 1: coalesced float4 tile load (256 rows x 32 f32) -> LDS (stride 33)
//   phase 2: one row per thread.
//     loss: sum_k d*softmax(-d) via __expf (threshold-checked output, rel err ~1e-6)
//     argmax(softmax(-100 d)) == first-occurrence argmax(z), z=-100d, UNLESS an
//       earlier index ties after exp/divide rounding -- requires z_j >= m - ~2^-23.
//       Conservative guard (2.4e-7) takes the exact expf+IEEE-div replication only
//       then (exec-masked, ~never in practice). Bit-faithful to fp32 numpy ref.
//   phase 3: 100 fully-coalesced float4 stores per block (contiguous 400 KB).
//   loss: block partial sums -> d_ws (NO atomics: fp64 atomicAdd is a CAS retry
//   loop on gfx950 without unsafe-fp-atomics; 8192-way contention was pathological),
//   finalize kernel reduces 2048 partials.

constexpr int kB      = 524288;
constexpr int kF      = 16;
constexpr int kK1     = 16;
constexpr int kK2     = 8;
constexpr int kRowIn  = 32;    // DISC + F
constexpr int kRowOut = 400;   // DISC + F*K1 + F*K2
constexpr float kEps  = 0.001f;
constexpr int kTPB    = 256;   // threads per block == rows per block
constexpr int kGrid   = kB / kTPB;     // 2048 blocks
constexpr int kC4     = kRowOut / 4;   // 100 float4 chunks per row
constexpr int kXStride = 33;   // LDS row stride in floats (conflict-free)

template <int K>
__device__ __forceinline__ int soft_argmax_loss(const float* __restrict__ dd,
                                                double& lacc)
{
#pragma clang fp contract(off)
    // ---- loss term: sum_k d * softmax(-d). Fast exp: output is threshold-checked.
    float se = 0.f, sde = 0.f;
#pragma unroll
    for (int k = 0; k < K; ++k) {
        float e = __expf(-dd[k]);
        se += e; sde += dd[k] * e;
    }
    lacc += (double)(sde / se);

    // ---- argmax(softmax(-100*d)) fast path: first-occurrence argmax of z ----
    float z[K];
#pragma unroll
    for (int k = 0; k < K; ++k) z[k] = -100.0f * dd[k];
    float m = z[0]; int kmax = 0;
#pragma unroll
    for (int k = 1; k < K; ++k) {
        if (z[k] > m) { m = z[k]; kmax = k; }
    }

    // softmax is a monotone-nondecreasing transform of z, so argmax can only
    // move to an EARLIER index j<kmax whose p_j rounds equal to p_kmax. That
    // needs exp(z_j-m) to round within ~1 ulp of exp(0)=1, i.e. z_j-m >= ~-1.2e-7.
    // (For large |m|, distinct z differ by >> that, so only exact ties pass.)
    bool cand = false;
#pragma unroll
    for (int k = 0; k < K; ++k)
        cand |= (k < kmax) & (z[k] >= m - 2.4e-7f);
    if (cand) {
        // exact replication of the fp32 reference: accurate expf, ordered sum,
        // IEEE divides, strict-> first-occurrence scan.
        float e2[K]; float ss = 0.f;
        for (int k = 0; k < K; ++k) { e2[k] = expf(z[k] - m); ss += e2[k]; }
        int km = 0; float pmax = e2[0] / ss;
        for (int k = 1; k < K; ++k) {
            float p = e2[k] / ss;
            if (p > pmax) { pmax = p; km = k; }
        }
        kmax = km;
    }
    return kmax;
}

__global__ __launch_bounds__(kTPB) void binlayer_main(
    const float* __restrict__ x,
    const float* __restrict__ interval,
    const float* __restrict__ interval2,
    const float* __restrict__ i_min,
    float* __restrict__ out,
    double* __restrict__ partial)
{
#pragma clang fp contract(off)
    __shared__ float sC1[kF][kK1];
    __shared__ float sC2[kF][kK2];
    __shared__ float sX[kTPB * kXStride];
    __shared__ unsigned char sIdx[kTPB * kF];
    __shared__ double sL[kTPB / 64];

    const int tid = threadIdx.x;

    // centers: i_min + fp32 cumsum of max(interval, eps), in k order
    if (tid < kF) {
        const float base = i_min[tid];
        float run = 0.f;
        for (int k = 0; k < kK1; ++k) {
            run += fmaxf(interval[tid * kK1 + k], kEps);
            sC1[tid][k] = base + run;
        }
        run = 0.f;
        for (int k = 0; k < kK2; ++k) {
            run += fmaxf(interval2[tid * kK2 + k], kEps);
            sC2[tid][k] = base + run;
        }
    }

    const long long rowBase = (long long)blockIdx.x * kTPB;

    // ---------------- phase 1: coalesced tile load -> LDS ----------------
    const float4* __restrict__ xin4 = (const float4*)(x + rowBase * kRowIn);
#pragma unroll
    for (int i = 0; i < (kTPB * kRowIn / 4) / kTPB; ++i) {   // 8 iters
        int flat = i * kTPB + tid;                 // 0..2047 float4s
        float4 v = xin4[flat];
        int r = flat >> 3, c4 = flat & 7;
        float* p = &sX[r * kXStride + c4 * 4];
        p[0] = v.x; p[1] = v.y; p[2] = v.z; p[3] = v.w;
    }
    __syncthreads();

    // ---------------- phase 2: one row per thread ----------------
    double lacc = 0.0;
    const float* __restrict__ myc = &sX[tid * kXStride + 16];

#pragma unroll 1
    for (int f = 0; f < kF; ++f) {
        const float c = myc[f];

        float dd1[kK1];
#pragma unroll
        for (int k = 0; k < kK1; ++k) { float t = c - sC1[f][k]; dd1[k] = t * t; }
        int k1 = soft_argmax_loss<kK1>(dd1, lacc);

        float dd2[kK2];
#pragma unroll
        for (int k = 0; k < kK2; ++k) { float t = c - sC2[f][k]; dd2[k] = t * t; }
        int k2 = soft_argmax_loss<kK2>(dd2, lacc);

        sIdx[tid * kF + f] = (unsigned char)(k1 | (k2 << 4));
    }

    // loss: wave shuffle-reduce -> LDS -> one plain store per block (no atomics)
#pragma unroll
    for (int off = 32; off > 0; off >>= 1) lacc += __shfl_down(lacc, off);
    if ((tid & 63) == 0) sL[tid >> 6] = lacc;

    __syncthreads();   // covers sIdx visibility for phase 3 and sL for tid 0

    if (tid == 0) partial[blockIdx.x] = sL[0] + sL[1] + sL[2] + sL[3];

    // ---------------- phase 3: fully coalesced stores ----------------
    float4* __restrict__ o4 = (float4*)(out + rowBase * kRowOut);
#pragma unroll 1
    for (int i = 0; i < kC4; ++i) {                  // 100 iters
        unsigned idx = (unsigned)(i * kTPB + tid);   // 0..25599
        unsigned r = idx / 100u;                     // row in tile
        unsigned c = idx - r * 100u;                 // float4 chunk in row
        float4 o;
        if (c < 4u) {
            const float* p = &sX[r * kXStride + c * 4u];
            o.x = p[0]; o.y = p[1]; o.z = p[2]; o.w = p[3];
        } else if (c < 68u) {
            unsigned u = c - 4u, f = u >> 2, q = (u & 3u) * 4u;
            unsigned k = sIdx[r * kF + f] & 15u;
            o.x = (k == q + 0u) ? 1.f : 0.f;
            o.y = (k == q + 1u) ? 1.f : 0.f;
            o.z = (k == q + 2u) ? 1.f : 0.f;
            o.w = (k == q + 3u) ? 1.f : 0.f;
        } else {
            unsigned u = c - 68u, f = u >> 1, q = (u & 1u) * 4u;
            unsigned k = (unsigned)(sIdx[r * kF + f]) >> 4;
            o.x = (k == q + 0u) ? 1.f : 0.f;
            o.y = (k == q + 1u) ? 1.f : 0.f;
            o.z = (k == q + 2u) ? 1.f : 0.f;
            o.w = (k == q + 3u) ? 1.f : 0.f;
        }
        o4[idx] = o;
    }
}

__global__ __launch_bounds__(256) void binlayer_finalize(
    const double* __restrict__ partial,
    float* __restrict__ out)
{
    __shared__ double sL[4];
    const int tid = threadIdx.x;
    double s = 0.0;
#pragma unroll
    for (int i = 0; i < kGrid / 256; ++i)       // 8 values each
        s += partial[i * 256 + tid];
#pragma unroll
    for (int off = 32; off > 0; off >>= 1) s += __shfl_down(s, off);
    if ((tid & 63) == 0) sL[tid >> 6] = s;
    __syncthreads();
    if (tid == 0)
        out[(long long)kB * kRowOut] =
            (float)((sL[0] + sL[1] + sL[2] + sL[3]) * (1.0 / (double)kB));
}

extern "C" void kernel_launch(void* const* d_in, const int* in_sizes, int n_in,
                              void* d_out, int out_size, void* d_ws, size_t ws_size,
                              hipStream_t stream)
{
    const float* x    = (const float*)d_in[0];
    const float* itv1 = (const float*)d_in[1];
    const float* itv2 = (const float*)d_in[2];
    const float* imin = (const float*)d_in[3];
    float* out = (float*)d_out;
    double* partial = (double*)d_ws;   // kGrid doubles = 16 KB

    binlayer_main<<<kGrid, kTPB, 0, stream>>>(x, itv1, itv2, imin, out, partial);
    binlayer_finalize<<<1, 256, 0, stream>>>(partial, out);
}